// Round 19
// baseline (310.048 us; speedup 1.0000x reference)
//
#include <hip/hip_runtime.h>
#include <math.h>

#define BB 256
#define VV 4096
#define DD 64
#define NCH 16      // 16 chunks x 16 rows per wave (wave owns 256 rows)

typedef __attribute__((ext_vector_type(8))) _Float16 f16x8;
typedef __attribute__((ext_vector_type(2))) __fp16 fp16x2;   // cvt_pkrtz return type
typedef __attribute__((ext_vector_type(4))) float f32x4;

// ---------------------------------------------------------------------------
// Kernel 1: 1024 blocks of 256 thr = (a, v-quarter); 4 waves/block, wave w
// owns rows [1024*quarter + 256*w, +256) x ALL 256 cols.
// r3's design (direct fragment-order global loads, NO LDS, NO barriers in
// the loop) fixed per the session's lessons:
//  - 256-thr blocks: the 128-VGPR cap applies to 512-thr blocks (r6/r7);
//    bf[16][2] (128 VGPR) + depth-3 pipe (~220 total) fits under 256.
//  - depth-3 STATIC-NAMED prefetch (rule #20), compiler-managed waitcnt.
// Each wave free-runs: vmem delivery overlaps the other wave's MFMA/VALU on
// the same SIMD with no lockstep (r11-r18: every barrier variant lost).
// Per-(a,quarter) partials after a tiny 4-wave LDS merge; lse merges 4.
// ---------------------------------------------------------------------------
__global__ __launch_bounds__(256, 2) void topk_sim_kernel(
    const float* __restrict__ F, const float* __restrict__ lan,
    float* __restrict__ max0P, float* __restrict__ max1P)
{
  __shared__ float mrg[4][BB][2];   // 8 KB merge buffer (epilogue only)
  const int t = threadIdx.x;
  const int a       = blockIdx.x >> 2;
  const int quarter = blockIdx.x & 3;
  const int wave = t >> 6;
  const int lane = t & 63;
  const int cl = lane & 15;      // A-row / B-col / C-col within 16x16 tile
  const int o  = lane >> 4;      // k-octet group

  // ---- B fragments for all 16 col-tiles, fp16; 4 groups of 4 ct to cap
  //      transient VGPRs (r16 lesson) ----
  f16x8 bf[16][2];
#pragma unroll
  for (int g = 0; g < 4; ++g) {
    float4 bu4[4][2][2];
#pragma unroll
    for (int ci = 0; ci < 4; ++ci)
#pragma unroll
      for (int s = 0; s < 2; ++s) {
        const float* p = lan + ((g * 4 + ci) * 16 + cl) * DD + s * 32 + o * 8;
        bu4[ci][s][0] = *(const float4*)p;
        bu4[ci][s][1] = *(const float4*)(p + 4);
      }
#pragma unroll
    for (int ci = 0; ci < 4; ++ci)
#pragma unroll
      for (int s = 0; s < 2; ++s) {
        union { f16x8 v; fp16x2 h[4]; } U;
        U.h[0] = __builtin_amdgcn_cvt_pkrtz(bu4[ci][s][0].x, bu4[ci][s][0].y);
        U.h[1] = __builtin_amdgcn_cvt_pkrtz(bu4[ci][s][0].z, bu4[ci][s][0].w);
        U.h[2] = __builtin_amdgcn_cvt_pkrtz(bu4[ci][s][1].x, bu4[ci][s][1].y);
        U.h[3] = __builtin_amdgcn_cvt_pkrtz(bu4[ci][s][1].z, bu4[ci][s][1].w);
        bf[g * 4 + ci][s] = U.v;
      }
  }

  float m0[16], m1[16];
#pragma unroll
  for (int ct = 0; ct < 16; ++ct) { m0[ct] = -INFINITY; m1[ct] = -INFINITY; }

  // per-lane base: row = 1024*quarter + 256*wave + chunk*16 + cl, octet o
  const float* Fa = F + (size_t)a * VV * DD
                    + (size_t)(quarter * 1024 + wave * 256) * DD
                    + cl * DD + o * 8;

#define LOADC(S0, S1, S2, S3, CH) {                                  \
    const float* _p = Fa + (size_t)(CH) * 16 * DD;                   \
    S0 = *(const float4*)(_p);      S1 = *(const float4*)(_p + 4);   \
    S2 = *(const float4*)(_p + 32); S3 = *(const float4*)(_p + 36); }

#define STAGE(S0, S1, S2, S3, CH, REFILL) {                          \
    union { f16x8 v; fp16x2 h[4]; } A0u, A1u;                        \
    A0u.h[0] = __builtin_amdgcn_cvt_pkrtz(S0.x, S0.y);               \
    A0u.h[1] = __builtin_amdgcn_cvt_pkrtz(S0.z, S0.w);               \
    A0u.h[2] = __builtin_amdgcn_cvt_pkrtz(S1.x, S1.y);               \
    A0u.h[3] = __builtin_amdgcn_cvt_pkrtz(S1.z, S1.w);               \
    A1u.h[0] = __builtin_amdgcn_cvt_pkrtz(S2.x, S2.y);               \
    A1u.h[1] = __builtin_amdgcn_cvt_pkrtz(S2.z, S2.w);               \
    A1u.h[2] = __builtin_amdgcn_cvt_pkrtz(S3.x, S3.y);               \
    A1u.h[3] = __builtin_amdgcn_cvt_pkrtz(S3.z, S3.w);               \
    f16x8 a0 = A0u.v, a1 = A1u.v;                                    \
    if (REFILL) LOADC(S0, S1, S2, S3, (CH) + 3)                      \
    _Pragma("unroll")                                                \
    for (int ct = 0; ct < 16; ++ct) {                                \
      f32x4 acc = {0.f, 0.f, 0.f, 0.f};                              \
      acc = __builtin_amdgcn_mfma_f32_16x16x32_f16(a0, bf[ct][0], acc, 0, 0, 0); \
      acc = __builtin_amdgcn_mfma_f32_16x16x32_f16(a1, bf[ct][1], acc, 0, 0, 0); \
      float h1 = fmaxf(acc[0], acc[1]), q1 = fminf(acc[0], acc[1]);  \
      float h2 = fmaxf(acc[2], acc[3]), q2 = fminf(acc[2], acc[3]);  \
      float M0 = fmaxf(h1, h2);                                      \
      float M1 = fmaxf(fminf(h1, h2), fmaxf(q1, q2));                \
      float old0 = m0[ct];                                           \
      m0[ct] = fmaxf(old0, M0);                                      \
      m1[ct] = fmaxf(m1[ct], fmaxf(fminf(old0, M0), M1));            \
    }                                                                \
  }

  // ---- depth-3 statically-named pipeline over 16 chunks, no barriers ----
  float4 A0, A1, A2, A3, B0, B1, B2, B3, C0, C1, C2, C3;
  LOADC(A0, A1, A2, A3, 0)
  LOADC(B0, B1, B2, B3, 1)
  LOADC(C0, C1, C2, C3, 2)

#pragma unroll 1
  for (int q = 0; q < 5; ++q) {
    const int ch = 3 * q;                        // 0,3,6,9,12
    STAGE(A0, A1, A2, A3, ch,     ch + 3 < NCH)  // refills 3..15
    STAGE(B0, B1, B2, B3, ch + 1, ch + 4 < NCH)
    STAGE(C0, C1, C2, C3, ch + 2, ch + 5 < NCH)
  }
  STAGE(A0, A1, A2, A3, 15, 0)                   // chunk 15 (loaded at q=4)
#undef STAGE
#undef LOADC

  // ---- merge across the 4 k-octet groups within the wave ----
#pragma unroll
  for (int ct = 0; ct < 16; ++ct) {
#pragma unroll
    for (int off = 16; off <= 32; off <<= 1) {
      float p0 = __shfl_xor(m0[ct], off);
      float p1 = __shfl_xor(m1[ct], off);
      float n1 = fmaxf(fminf(m0[ct], p0), fmaxf(m1[ct], p1));
      m0[ct] = fmaxf(m0[ct], p0);
      m1[ct] = n1;
    }
    if (lane < 16) {
      mrg[wave][ct * 16 + lane][0] = m0[ct];
      mrg[wave][ct * 16 + lane][1] = m1[ct];
    }
  }
  __syncthreads();

  // ---- merge the 4 waves' row-slices; store per-(a,quarter) partial ----
  if (t < BB) {
    float M0 = -INFINITY, M1 = -INFINITY;
#pragma unroll
    for (int w = 0; w < 4; ++w) {
      float a0 = mrg[w][t][0], a1 = mrg[w][t][1];
      float n1 = fmaxf(fminf(M0, a0), fmaxf(M1, a1));
      M0 = fmaxf(M0, a0);
      M1 = n1;
    }
    max0P[((size_t)a * 4 + quarter) * BB + t] = M0;
    max1P[((size_t)a * 4 + quarter) * BB + t] = M1;
  }
}

// ---------------------------------------------------------------------------
// Kernel 2: per row b, merge the 4 v-quarter partials per a, LSE over 511
// logits, loss_b = LSE - diag.
// ---------------------------------------------------------------------------
__global__ __launch_bounds__(256) void lse_kernel(
    const float* __restrict__ max0P, const float* __restrict__ max1P,
    float* __restrict__ lossb)
{
  __shared__ float red[256];
  __shared__ float diag;
  const int b = blockIdx.x;
  const int t = threadIdx.x;     // t = a
  float M0 = -INFINITY, M1 = -INFINITY;
#pragma unroll
  for (int q = 0; q < 4; ++q) {
    float p0 = max0P[((size_t)t * 4 + q) * BB + b];
    float p1 = max1P[((size_t)t * 4 + q) * BB + b];
    float n1 = fmaxf(fminf(M0, p0), fmaxf(M1, p1));
    M0 = fmaxf(M0, p0);
    M1 = n1;
  }
  float x0 = M0;
  float x1 = (t == b) ? -INFINITY : M1;
  if (t == b) diag = x0;
  red[t] = fmaxf(x0, x1);
  __syncthreads();
  for (int s = 128; s > 0; s >>= 1) {
    if (t < s) red[t] = fmaxf(red[t], red[t + s]);
    __syncthreads();
  }
  float M = red[0];
  __syncthreads();
  float e = expf(x0 - M) + ((t == b) ? 0.0f : expf(x1 - M));
  red[t] = e;
  __syncthreads();
  for (int s = 128; s > 0; s >>= 1) {
    if (t < s) red[t] = red[t] + red[t + s];
    __syncthreads();
  }
  if (t == 0) lossb[b] = logf(red[0]) + M - diag;
}

__global__ __launch_bounds__(256) void mean_kernel(
    const float* __restrict__ lossb, float* __restrict__ out)
{
  __shared__ float red[256];
  const int t = threadIdx.x;
  red[t] = lossb[t];
  __syncthreads();
  for (int s = 128; s > 0; s >>= 1) {
    if (t < s) red[t] += red[t + s];
    __syncthreads();
  }
  if (t == 0) out[0] = red[0] * (1.0f / 256.0f);
}

extern "C" void kernel_launch(void* const* d_in, const int* in_sizes, int n_in,
                              void* d_out, int out_size, void* d_ws, size_t ws_size,
                              hipStream_t stream) {
  const float* F   = (const float*)d_in[0];   // fusion_fs [256,4096,64] fp32
  const float* lan = (const float*)d_in[1];   // lan_fs    [256,1,64]   fp32
  float* ws = (float*)d_ws;
  float* max0P = ws;                // [256*4*256] = 1 MB
  float* max1P = ws + 262144;       // [256*4*256] = 1 MB
  float* lossb = ws + 524288;       // [256]

  topk_sim_kernel<<<1024, 256, 0, stream>>>(F, lan, max0P, max1P);
  lse_kernel<<<256, 256, 0, stream>>>(max0P, max1P, lossb);
  mean_kernel<<<1, 256, 0, stream>>>(lossb, (float*)d_out);
}

// Round 20
// 73.096 us; speedup vs baseline: 4.2416x; 4.2416x over previous
//
#include <hip/hip_runtime.h>
#include <math.h>

#define BB 256
#define VV 4096
#define DD 64
#define NCHUNK 16    // per block: 2048 rows in 16 chunks of 128 rows
#define CHBG 32768   // global chunk bytes: 128 rows x 64 d x 4 B (fp32)
#define CHBL 16384   // LDS chunk bytes:    128 rows x 64 d x 2 B (fp16)

typedef __attribute__((ext_vector_type(8))) _Float16 f16x8;
typedef __attribute__((ext_vector_type(2))) __fp16 fp16x2;   // cvt_pkrtz return type
typedef __attribute__((ext_vector_type(4))) float f32x4;

// ---------------------------------------------------------------------------
// Kernel 1: 512 blocks of 512 thr = (a, v-half); the r17 champion kernel
// (fp16 reg-staging, E/O static-named depth-2, counted vmcnt(4), one raw
// s_barrier per chunk, wave = 2 rowgroups x 4 colgroups) with ONE variable
// changed: 2 co-resident blocks/CU (36 KB LDS each) -> two independent
// barrier domains overlap each other's barrier/delivery stalls, 4 waves/SIMD.
// r12/r18 changed granule+wave-count simultaneously and lost; this isolates
// the occupancy axis at r17's proven granule/schedule.
// ---------------------------------------------------------------------------
__global__ __launch_bounds__(512) void topk_sim_kernel(
    const float* __restrict__ F, const float* __restrict__ lan,
    float* __restrict__ max0P, float* __restrict__ max1P)
{
  extern __shared__ __align__(16) char smem[];   // 2 x 16KB fp16 chunk buffers
  __shared__ float mrg[8][64][2];                // 4 KB merge buffer

  const int t = threadIdx.x;
  const int a    = blockIdx.x >> 1;
  const int half = blockIdx.x & 1;
  const int wave = t >> 6;
  const int lane = t & 63;
  const int cl = lane & 15;      // row (A) / col (B/C) within 16x16 tile
  const int o  = lane >> 4;      // k-octet group
  const int rg = wave >> 2;      // row half (of the 128-row chunk)
  const int cg = wave & 3;       // col quarter

  const char* gFa = (const char*)(F + (size_t)a * VV * DD
                                  + (size_t)half * 2048 * DD);

  // ---- B fragment loads + cvt (all vmem retired before F pipeline) ----
  float4 bu[4][2][2];
#pragma unroll
  for (int ct = 0; ct < 4; ++ct)
#pragma unroll
    for (int s = 0; s < 2; ++s) {
      const float* p = lan + (cg * 64 + ct * 16 + cl) * DD + s * 32 + o * 8;
      bu[ct][s][0] = *(const float4*)p;
      bu[ct][s][1] = *(const float4*)(p + 4);
    }
  f16x8 bf[4][2];
#pragma unroll
  for (int ct = 0; ct < 4; ++ct)
#pragma unroll
    for (int s = 0; s < 2; ++s) {
      union { f16x8 v; fp16x2 h[4]; } U;
      U.h[0] = __builtin_amdgcn_cvt_pkrtz(bu[ct][s][0].x, bu[ct][s][0].y);
      U.h[1] = __builtin_amdgcn_cvt_pkrtz(bu[ct][s][0].z, bu[ct][s][0].w);
      U.h[2] = __builtin_amdgcn_cvt_pkrtz(bu[ct][s][1].x, bu[ct][s][1].y);
      U.h[3] = __builtin_amdgcn_cvt_pkrtz(bu[ct][s][1].z, bu[ct][s][1].w);
      bf[ct][s] = U.v;
    }

  // ---- staging addressing (identical to r17) ----
  const int woff = ((((t & 15) >> 1) ^ ((t >> 4) & 7)) << 4) + (t & 1) * 8;
  const int wrow = (t >> 4) * 128;               // + i*4096 per instr

#define LOADG(S0, S1, S2, S3, CH) {                                   \
    const char* _g = gFa + (size_t)(CH) * CHBG + 16 * t;              \
    S0 = *(const float4*)(_g);                                        \
    S1 = *(const float4*)(_g + 8192);                                 \
    S2 = *(const float4*)(_g + 16384);                                \
    S3 = *(const float4*)(_g + 24576); }

#define CVTW(S0, S1, S2, S3, BUFP) {                                  \
    char* _b = (BUFP) + wrow + woff;                                  \
    union { uint2 u; fp16x2 h[2]; } _c;                               \
    _c.h[0] = __builtin_amdgcn_cvt_pkrtz(S0.x, S0.y);                 \
    _c.h[1] = __builtin_amdgcn_cvt_pkrtz(S0.z, S0.w);                 \
    *(uint2*)(_b) = _c.u;                                             \
    _c.h[0] = __builtin_amdgcn_cvt_pkrtz(S1.x, S1.y);                 \
    _c.h[1] = __builtin_amdgcn_cvt_pkrtz(S1.z, S1.w);                 \
    *(uint2*)(_b + 4096) = _c.u;                                      \
    _c.h[0] = __builtin_amdgcn_cvt_pkrtz(S2.x, S2.y);                 \
    _c.h[1] = __builtin_amdgcn_cvt_pkrtz(S2.z, S2.w);                 \
    *(uint2*)(_b + 8192) = _c.u;                                      \
    _c.h[0] = __builtin_amdgcn_cvt_pkrtz(S3.x, S3.y);                 \
    _c.h[1] = __builtin_amdgcn_cvt_pkrtz(S3.z, S3.w);                 \
    *(uint2*)(_b + 12288) = _c.u; }

  float m0[4], m1[4];
#pragma unroll
  for (int ct = 0; ct < 4; ++ct) { m0[ct] = -INFINITY; m1[ct] = -INFINITY; }

  auto compute = [&](const char* buf) {
#pragma unroll
    for (int rt = 0; rt < 4; ++rt) {
      const int row = rg * 64 + rt * 16 + cl;
      const int rx = cl & 7;                     // row&7 == cl&7
      const char* lp = buf + row * 128;
      f16x8 a0 = *(const f16x8*)(lp + ((o ^ rx) << 4));         // ksub 0
      f16x8 a1 = *(const f16x8*)(lp + (((4 + o) ^ rx) << 4));   // ksub 1
#pragma unroll
      for (int ct = 0; ct < 4; ++ct) {
        f32x4 acc = {0.f, 0.f, 0.f, 0.f};
        acc = __builtin_amdgcn_mfma_f32_16x16x32_f16(a0, bf[ct][0], acc, 0, 0, 0);
        acc = __builtin_amdgcn_mfma_f32_16x16x32_f16(a1, bf[ct][1], acc, 0, 0, 0);
        float h1 = fmaxf(acc[0], acc[1]), q1 = fminf(acc[0], acc[1]);
        float h2 = fmaxf(acc[2], acc[3]), q2 = fminf(acc[2], acc[3]);
        float M0 = fmaxf(h1, h2);
        float M1 = fmaxf(fminf(h1, h2), fmaxf(q1, q2));
        float old0 = m0[ct];
        m0[ct] = fmaxf(old0, M0);
        m1[ct] = fmaxf(m1[ct], fmaxf(fminf(old0, M0), M1));
      }
    }
  };

  char* buf0 = smem;
  char* buf1 = smem + CHBL;

  // ---- prologue: E=chunk0, O=chunk1; write chunk0 -> buf0; barrier ----
  float4 E0, E1, E2, E3, O0, O1, O2, O3;
  LOADG(E0, E1, E2, E3, 0)
  LOADG(O0, O1, O2, O3, 1)
  asm volatile("s_waitcnt vmcnt(4)" ::: "memory");   // E delivered
  CVTW(E0, E1, E2, E3, buf0)
  asm volatile("s_waitcnt lgkmcnt(0)" ::: "memory");
  __builtin_amdgcn_s_barrier();

  // ---- main loop: 7 x 2 chunks (0..13 computed; 14,15 in tail) ----
#pragma unroll 1
  for (int q = 0; q < 7; ++q) {
    const int ch = 2 * q;
    LOADG(E0, E1, E2, E3, ch + 2)
    asm volatile("s_waitcnt vmcnt(4)" ::: "memory");   // O ready
    __builtin_amdgcn_sched_barrier(0);
    CVTW(O0, O1, O2, O3, buf1)
    compute(buf0);
    asm volatile("s_waitcnt lgkmcnt(0)" ::: "memory");
    __builtin_amdgcn_s_barrier();
    LOADG(O0, O1, O2, O3, ch + 3)
    asm volatile("s_waitcnt vmcnt(4)" ::: "memory");   // E ready
    __builtin_amdgcn_sched_barrier(0);
    CVTW(E0, E1, E2, E3, buf0)
    compute(buf1);
    asm volatile("s_waitcnt lgkmcnt(0)" ::: "memory");
    __builtin_amdgcn_s_barrier();
  }
  // ---- tail: chunks 14 (buf0), 15 (buf1) ----
  asm volatile("s_waitcnt vmcnt(0)" ::: "memory");
  __builtin_amdgcn_sched_barrier(0);
  CVTW(O0, O1, O2, O3, buf1)
  compute(buf0);
  asm volatile("s_waitcnt lgkmcnt(0)" ::: "memory");
  __builtin_amdgcn_s_barrier();
  compute(buf1);
#undef LOADG
#undef CVTW

  // ---- merge across the 4 k-octet row-groups within the wave ----
#pragma unroll
  for (int ct = 0; ct < 4; ++ct) {
#pragma unroll
    for (int off = 16; off <= 32; off <<= 1) {
      float p0 = __shfl_xor(m0[ct], off);
      float p1 = __shfl_xor(m1[ct], off);
      float n1 = fmaxf(fminf(m0[ct], p0), fmaxf(m1[ct], p1));
      m0[ct] = fmaxf(m0[ct], p0);
      m1[ct] = n1;
    }
    if (lane < 16) {
      mrg[wave][ct * 16 + lane][0] = m0[ct];
      mrg[wave][ct * 16 + lane][1] = m1[ct];
    }
  }
  __syncthreads();

  // ---- merge the 2 row-half waves of each col group; store partial ----
  if (t < BB) {
    const int cg2 = t >> 6, lc = t & 63;   // global col == t
    float a0 = mrg[cg2][lc][0],     a1 = mrg[cg2][lc][1];
    float b0 = mrg[4 + cg2][lc][0], b1 = mrg[4 + cg2][lc][1];
    float M0 = fmaxf(a0, b0);
    float M1 = fmaxf(fminf(a0, b0), fmaxf(a1, b1));
    max0P[((size_t)a * 2 + half) * BB + t] = M0;
    max1P[((size_t)a * 2 + half) * BB + t] = M1;
  }
}

// ---------------------------------------------------------------------------
// Kernel 2: per row b, merge the two v-half partials per a, LSE over 511
// logits, loss_b = LSE - diag.
// ---------------------------------------------------------------------------
__global__ __launch_bounds__(256) void lse_kernel(
    const float* __restrict__ max0P, const float* __restrict__ max1P,
    float* __restrict__ lossb)
{
  __shared__ float red[256];
  __shared__ float diag;
  const int b = blockIdx.x;
  const int t = threadIdx.x;     // t = a
  float p00 = max0P[((size_t)t * 2 + 0) * BB + b];
  float p01 = max0P[((size_t)t * 2 + 1) * BB + b];
  float p10 = max1P[((size_t)t * 2 + 0) * BB + b];
  float p11 = max1P[((size_t)t * 2 + 1) * BB + b];
  float x0 = fmaxf(p00, p01);
  float x1m = fmaxf(fminf(p00, p01), fmaxf(p10, p11));
  float x1 = (t == b) ? -INFINITY : x1m;
  if (t == b) diag = x0;
  red[t] = fmaxf(x0, x1);
  __syncthreads();
  for (int s = 128; s > 0; s >>= 1) {
    if (t < s) red[t] = fmaxf(red[t], red[t + s]);
    __syncthreads();
  }
  float M = red[0];
  __syncthreads();
  float e = expf(x0 - M) + ((t == b) ? 0.0f : expf(x1 - M));
  red[t] = e;
  __syncthreads();
  for (int s = 128; s > 0; s >>= 1) {
    if (t < s) red[t] = red[t] + red[t + s];
    __syncthreads();
  }
  if (t == 0) lossb[b] = logf(red[0]) + M - diag;
}

__global__ __launch_bounds__(256) void mean_kernel(
    const float* __restrict__ lossb, float* __restrict__ out)
{
  __shared__ float red[256];
  const int t = threadIdx.x;
  red[t] = lossb[t];
  __syncthreads();
  for (int s = 128; s > 0; s >>= 1) {
    if (t < s) red[t] += red[t + s];
    __syncthreads();
  }
  if (t == 0) out[0] = red[0] * (1.0f / 256.0f);
}

extern "C" void kernel_launch(void* const* d_in, const int* in_sizes, int n_in,
                              void* d_out, int out_size, void* d_ws, size_t ws_size,
                              hipStream_t stream) {
  const float* F   = (const float*)d_in[0];   // fusion_fs [256,4096,64] fp32
  const float* lan = (const float*)d_in[1];   // lan_fs    [256,1,64]   fp32
  float* ws = (float*)d_ws;
  float* max0P = ws;                // [256*2*256]
  float* max1P = ws + 131072;       // [256*2*256]
  float* lossb = ws + 262144;       // [256]

  const int shmem = 2 * CHBL;       // 32 KB dynamic per block
  topk_sim_kernel<<<512, 512, shmem, stream>>>(F, lan, max0P, max1P);
  lse_kernel<<<256, 256, 0, stream>>>(max0P, max1P, lossb);
  mean_kernel<<<1, 256, 0, stream>>>(lossb, (float*)d_out);
}

// Round 21
// 66.440 us; speedup vs baseline: 4.6666x; 1.1002x over previous
//
#include <hip/hip_runtime.h>
#include <math.h>

#define BB 256
#define VV 4096
#define DD 64
#define NCHUNK 32
#define CHBG 32768   // global chunk bytes: 128 rows x 64 d x 4 B (fp32)
#define CHBL 16384   // LDS chunk bytes:    128 rows x 64 d x 2 B (fp16)

typedef __attribute__((ext_vector_type(8))) _Float16 f16x8;
typedef __attribute__((ext_vector_type(2))) __fp16 fp16x2;   // cvt_pkrtz return type
typedef __attribute__((ext_vector_type(4))) float f32x4;

// ---------------------------------------------------------------------------
// CHAMPION (r17, 67.2us) restored verbatim. One block (512 thr, 8 waves)
// per a; wave = rg*4+cg.  F staged into LDS as FP16 via reg-staging (T14
// issue-early/write-late): each element cvt'd once per CU at stage time,
// LDS traffic/chunk 16KB write + 64KB read, compute = ds_read_b128 -> MFMA.
// Depth-2 static-named E/O reg pipeline (rule #20), counted vmcnt(4), ONE
// raw s_barrier per chunk, 2 LDS buffers (32 KB).
// Write swizzle: slot ^= row&7 (b64 floor); read: slot ^ (cl&7) (b128 floor).
// 9 structural probes around this config (r11-r16, r18-r20) all regressed;
// wins only ever came from byte/work reduction, now exhausted.
// ---------------------------------------------------------------------------
__global__ __launch_bounds__(512) void topk_sim_kernel(
    const float* __restrict__ F, const float* __restrict__ lan,
    float* __restrict__ max0T, float* __restrict__ max1T)
{
  extern __shared__ __align__(16) char smem[];   // 2 x 16KB fp16 chunk buffers
  __shared__ float mrg[8][64][2];                // 4 KB merge buffer

  const int t = threadIdx.x;
  const int a = blockIdx.x;
  const int wave = t >> 6;
  const int lane = t & 63;
  const int cl = lane & 15;      // row (A) / col (B/C) within 16x16 tile
  const int o  = lane >> 4;      // k-octet group
  const int rg = wave >> 2;      // row half
  const int cg = wave & 3;       // col quarter

  const char* gFa = (const char*)(F + (size_t)a * VV * DD);

  // ---- B fragment loads + cvt (all vmem retired before F pipeline) ----
  float4 bu[4][2][2];
#pragma unroll
  for (int ct = 0; ct < 4; ++ct)
#pragma unroll
    for (int s = 0; s < 2; ++s) {
      const float* p = lan + (cg * 64 + ct * 16 + cl) * DD + s * 32 + o * 8;
      bu[ct][s][0] = *(const float4*)p;
      bu[ct][s][1] = *(const float4*)(p + 4);
    }
  f16x8 bf[4][2];
#pragma unroll
  for (int ct = 0; ct < 4; ++ct)
#pragma unroll
    for (int s = 0; s < 2; ++s) {
      union { f16x8 v; fp16x2 h[4]; } U;
      U.h[0] = __builtin_amdgcn_cvt_pkrtz(bu[ct][s][0].x, bu[ct][s][0].y);
      U.h[1] = __builtin_amdgcn_cvt_pkrtz(bu[ct][s][0].z, bu[ct][s][0].w);
      U.h[2] = __builtin_amdgcn_cvt_pkrtz(bu[ct][s][1].x, bu[ct][s][1].y);
      U.h[3] = __builtin_amdgcn_cvt_pkrtz(bu[ct][s][1].z, bu[ct][s][1].w);
      bf[ct][s] = U.v;
    }

  // ---- staging addressing ----
  // load: instr i covers bytes [8192*i, 8192*i+8192) of the chunk; thread t
  // takes 16B at 8192*i + 16*t  -> row_i = 32*i + (t>>4), d0 = 4*(t&15).
  // write: fp16 8B at row_i*128 + swizzled slot; slot/half constant over i.
  const int woff = ((((t & 15) >> 1) ^ ((t >> 4) & 7)) << 4) + (t & 1) * 8;
  const int wrow = (t >> 4) * 128;               // + i*4096 per instr

#define LOADG(S0, S1, S2, S3, CH) {                                   \
    const char* _g = gFa + (size_t)(CH) * CHBG + 16 * t;              \
    S0 = *(const float4*)(_g);                                        \
    S1 = *(const float4*)(_g + 8192);                                 \
    S2 = *(const float4*)(_g + 16384);                                \
    S3 = *(const float4*)(_g + 24576); }

#define CVTW(S0, S1, S2, S3, BUFP) {                                  \
    char* _b = (BUFP) + wrow + woff;                                  \
    uint2 _w;                                                         \
    union { uint2 u; fp16x2 h[2]; } _c;                               \
    _c.h[0] = __builtin_amdgcn_cvt_pkrtz(S0.x, S0.y);                 \
    _c.h[1] = __builtin_amdgcn_cvt_pkrtz(S0.z, S0.w); _w = _c.u;      \
    *(uint2*)(_b) = _w;                                               \
    _c.h[0] = __builtin_amdgcn_cvt_pkrtz(S1.x, S1.y);                 \
    _c.h[1] = __builtin_amdgcn_cvt_pkrtz(S1.z, S1.w); _w = _c.u;      \
    *(uint2*)(_b + 4096) = _w;                                        \
    _c.h[0] = __builtin_amdgcn_cvt_pkrtz(S2.x, S2.y);                 \
    _c.h[1] = __builtin_amdgcn_cvt_pkrtz(S2.z, S2.w); _w = _c.u;      \
    *(uint2*)(_b + 8192) = _w;                                        \
    _c.h[0] = __builtin_amdgcn_cvt_pkrtz(S3.x, S3.y);                 \
    _c.h[1] = __builtin_amdgcn_cvt_pkrtz(S3.z, S3.w); _w = _c.u;      \
    *(uint2*)(_b + 12288) = _w; }

  float m0[4], m1[4];
#pragma unroll
  for (int ct = 0; ct < 4; ++ct) { m0[ct] = -INFINITY; m1[ct] = -INFINITY; }

  auto compute = [&](const char* buf) {
#pragma unroll
    for (int rt = 0; rt < 4; ++rt) {
      const int row = rg * 64 + rt * 16 + cl;
      const int rx = cl & 7;                     // row&7 == cl&7
      const char* lp = buf + row * 128;
      f16x8 a0 = *(const f16x8*)(lp + ((o ^ rx) << 4));         // ksub 0
      f16x8 a1 = *(const f16x8*)(lp + (((4 + o) ^ rx) << 4));   // ksub 1
#pragma unroll
      for (int ct = 0; ct < 4; ++ct) {
        f32x4 acc = {0.f, 0.f, 0.f, 0.f};
        acc = __builtin_amdgcn_mfma_f32_16x16x32_f16(a0, bf[ct][0], acc, 0, 0, 0);
        acc = __builtin_amdgcn_mfma_f32_16x16x32_f16(a1, bf[ct][1], acc, 0, 0, 0);
        float h1 = fmaxf(acc[0], acc[1]), q1 = fminf(acc[0], acc[1]);
        float h2 = fmaxf(acc[2], acc[3]), q2 = fminf(acc[2], acc[3]);
        float M0 = fmaxf(h1, h2);
        float M1 = fmaxf(fminf(h1, h2), fmaxf(q1, q2));
        float old0 = m0[ct];
        m0[ct] = fmaxf(old0, M0);
        m1[ct] = fmaxf(m1[ct], fmaxf(fminf(old0, M0), M1));
      }
    }
  };

  char* buf0 = smem;
  char* buf1 = smem + CHBL;

  // ---- prologue: E=chunk0, O=chunk1; write chunk0 -> buf0; barrier ----
  float4 E0, E1, E2, E3, O0, O1, O2, O3;
  LOADG(E0, E1, E2, E3, 0)
  LOADG(O0, O1, O2, O3, 1)
  asm volatile("s_waitcnt vmcnt(4)" ::: "memory");   // E delivered
  CVTW(E0, E1, E2, E3, buf0)
  asm volatile("s_waitcnt lgkmcnt(0)" ::: "memory");
  __builtin_amdgcn_s_barrier();

  // ---- main loop: 15 x 2 chunks, fully regular ----
#pragma unroll 1
  for (int q = 0; q < 15; ++q) {
    const int ch = 2 * q;
    // even: consume O(ch+1)->buf1, compute buf0(ch)
    LOADG(E0, E1, E2, E3, ch + 2)
    asm volatile("s_waitcnt vmcnt(4)" ::: "memory");   // O ready
    __builtin_amdgcn_sched_barrier(0);
    CVTW(O0, O1, O2, O3, buf1)
    compute(buf0);
    asm volatile("s_waitcnt lgkmcnt(0)" ::: "memory");
    __builtin_amdgcn_s_barrier();
    // odd: consume E(ch+2)->buf0, compute buf1(ch+1)
    LOADG(O0, O1, O2, O3, ch + 3)
    asm volatile("s_waitcnt vmcnt(4)" ::: "memory");   // E ready
    __builtin_amdgcn_sched_barrier(0);
    CVTW(E0, E1, E2, E3, buf0)
    compute(buf1);
    asm volatile("s_waitcnt lgkmcnt(0)" ::: "memory");
    __builtin_amdgcn_s_barrier();
  }
  // ---- tail: chunks 30 (buf0), 31 (buf1) ----
  asm volatile("s_waitcnt vmcnt(0)" ::: "memory");     // O(31) delivered
  __builtin_amdgcn_sched_barrier(0);
  CVTW(O0, O1, O2, O3, buf1)
  compute(buf0);
  asm volatile("s_waitcnt lgkmcnt(0)" ::: "memory");
  __builtin_amdgcn_s_barrier();
  compute(buf1);
#undef LOADG
#undef CVTW

  // ---- merge across the 4 k-octet row-groups within the wave ----
#pragma unroll
  for (int ct = 0; ct < 4; ++ct) {
#pragma unroll
    for (int off = 16; off <= 32; off <<= 1) {
      float p0 = __shfl_xor(m0[ct], off);
      float p1 = __shfl_xor(m1[ct], off);
      float n1 = fmaxf(fminf(m0[ct], p0), fmaxf(m1[ct], p1));
      m0[ct] = fmaxf(m0[ct], p0);
      m1[ct] = n1;
    }
    if (lane < 16) {
      mrg[wave][ct * 16 + lane][0] = m0[ct];
      mrg[wave][ct * 16 + lane][1] = m1[ct];
    }
  }
  __syncthreads();

  // ---- merge the 2 row-half waves of each col group; store ----
  if (t < BB) {
    const int cg2 = t >> 6, lc = t & 63;   // global col == t
    float a0 = mrg[cg2][lc][0],     a1 = mrg[cg2][lc][1];
    float b0 = mrg[4 + cg2][lc][0], b1 = mrg[4 + cg2][lc][1];
    float M0 = fmaxf(a0, b0);
    float M1 = fmaxf(fminf(a0, b0), fmaxf(a1, b1));
    max0T[a * BB + t] = M0;
    max1T[a * BB + t] = M1;
  }
}

// ---------------------------------------------------------------------------
// Kernel 2: per row b, LSE over 511 logits, loss_b = LSE - diag.
// ---------------------------------------------------------------------------
__global__ __launch_bounds__(256) void lse_kernel(
    const float* __restrict__ max0T, const float* __restrict__ max1T,
    float* __restrict__ lossb)
{
  __shared__ float red[256];
  __shared__ float diag;
  const int b = blockIdx.x;
  const int t = threadIdx.x;     // t = a
  float x0 = max0T[t * BB + b];
  float x1 = (t == b) ? -INFINITY : max1T[t * BB + b];
  if (t == b) diag = x0;
  red[t] = fmaxf(x0, x1);
  __syncthreads();
  for (int s = 128; s > 0; s >>= 1) {
    if (t < s) red[t] = fmaxf(red[t], red[t + s]);
    __syncthreads();
  }
  float M = red[0];
  __syncthreads();
  float e = expf(x0 - M) + ((t == b) ? 0.0f : expf(x1 - M));
  red[t] = e;
  __syncthreads();
  for (int s = 128; s > 0; s >>= 1) {
    if (t < s) red[t] = red[t] + red[t + s];
    __syncthreads();
  }
  if (t == 0) lossb[b] = logf(red[0]) + M - diag;
}

__global__ __launch_bounds__(256) void mean_kernel(
    const float* __restrict__ lossb, float* __restrict__ out)
{
  __shared__ float red[256];
  const int t = threadIdx.x;
  red[t] = lossb[t];
  __syncthreads();
  for (int s = 128; s > 0; s >>= 1) {
    if (t < s) red[t] += red[t + s];
    __syncthreads();
  }
  if (t == 0) out[0] = red[0] * (1.0f / 256.0f);
}

extern "C" void kernel_launch(void* const* d_in, const int* in_sizes, int n_in,
                              void* d_out, int out_size, void* d_ws, size_t ws_size,
                              hipStream_t stream) {
  const float* F   = (const float*)d_in[0];   // fusion_fs [256,4096,64] fp32
  const float* lan = (const float*)d_in[1];   // lan_fs    [256,1,64]   fp32
  float* ws = (float*)d_ws;
  float* max0T = ws;                // [256*256]
  float* max1T = ws + 65536;        // [256*256]
  float* lossb = ws + 131072;       // [256]

  const int shmem = 2 * CHBL;       // 32 KB dynamic
  topk_sim_kernel<<<256, 512, shmem, stream>>>(F, lan, max0T, max1T);
  lse_kernel<<<256, 256, 0, stream>>>(max0T, max1T, lossb);
  mean_kernel<<<1, 256, 0, stream>>>(lossb, (float*)d_out);
}